// Round 8
// baseline (207.280 us; speedup 1.0000x reference)
//
#include <hip/hip_runtime.h>
#include <hip/hip_bf16.h>

typedef __attribute__((ext_vector_type(8))) short short8;
typedef __attribute__((ext_vector_type(4))) float f32x4;

#define B_SZ 32
#define T_SZ 4096
#define H_SZ 512
#define NROWS (B_SZ * T_SZ)   // 131072

// packed fp32x2 -> bf16x2 (RNE), single v_cvt_pk_bf16_f32: a->low16, b->high16
static __device__ __forceinline__ unsigned int pack2(float a, float b) {
  unsigned int r;
  asm("v_cvt_pk_bf16_f32 %0, %1, %2" : "=v"(r) : "v"(a), "v"(b));
  return r;
}

// branch-free tanh, exact saturation at +/-inf: 1 - 2/(e^{2x}+1)
static __device__ __forceinline__ float fast_tanh(float x) {
  float e = __expf(2.0f * x);
  return 1.0f - 2.0f / (e + 1.0f);
}

// ---- W fp32 (512x512) -> bf16 in MFMA-fragment order ----
// fragment s = grow*64 + kt*4 + kslot; holds W[grow][kt*32 + kslot*8 .. +8]
// dst uint4 index = nb*1024 + kt*64 + (kslot*16 + g); a 16-g chunk = 16 KB contiguous
__global__ __launch_bounds__(256) void prep_w_kernel(
    const float* __restrict__ W, uint4* __restrict__ Wfrag) {
  int s = blockIdx.x * 256 + threadIdx.x;   // 0..32767
  int grow  = s >> 6;
  int kt    = (s >> 2) & 15;
  int kslot = s & 3;
  const float4* Wf4 = reinterpret_cast<const float4*>(W);
  float4 lo = Wf4[grow * 128 + kt * 8 + kslot * 2];
  float4 hi = Wf4[grow * 128 + kt * 8 + kslot * 2 + 1];
  uint4 u;
  u.x = pack2(lo.x, lo.y); u.y = pack2(lo.z, lo.w);
  u.z = pack2(hi.x, hi.y); u.w = pack2(hi.z, hi.w);
  int nb = grow >> 4, g = grow & 15;
  Wfrag[nb * 1024 + kt * 64 + kslot * 16 + g] = u;
}

// ---- fused: scores (MFMA, B direct-from-global/L1) + block softmax + num ----
// 512 thr = 8 waves, wave owns 16 rows -> block M=128, grid 1024.
// NO LDS and NO barriers in the main loop: B-frags are read straight from
// Wfrag (16 KB/chunk working set, L1-resident, identical across waves) --
// waves run free, TLP hides all latency. Block coordination only in the
// small softmax/num epilogue.
__global__ __launch_bounds__(512, 4) void score_fused_kernel(
    const float* __restrict__ X, const uint4* __restrict__ Wfrag,
    const float* __restrict__ v,
    float* __restrict__ num, float2* __restrict__ md) {
  __shared__ float sLDS[128];
  __shared__ float pLDS[128];
  __shared__ float mred[2], dred[2];

  const int tid   = threadIdx.x;
  const int lane  = tid & 63;
  const int wave  = tid >> 6;
  const int frow  = lane & 15;   // A: m row / B: g col
  const int kslot = lane >> 4;
  const size_t rowbase = (size_t)blockIdx.x * 128;
  const size_t arow = rowbase + wave * 16 + frow;

  // A fragments: X[arow][kt*32 + kslot*8 .. +8] for kt=0..15, bf16-packed (64 VGPR)
  short8 afrag[16];
  {
    const float4* xr = reinterpret_cast<const float4*>(X + arow * H_SZ);
    #pragma unroll
    for (int kt = 0; kt < 16; ++kt) {
      float4 lo = xr[kt * 8 + kslot * 2];
      float4 hi = xr[kt * 8 + kslot * 2 + 1];
      union { uint4 u; short8 s; } cv;
      cv.u.x = pack2(lo.x, lo.y); cv.u.y = pack2(lo.z, lo.w);
      cv.u.z = pack2(hi.x, hi.y); cv.u.w = pack2(hi.z, hi.w);
      afrag[kt] = cv.s;
    }
  }

  float red[4] = {0.f, 0.f, 0.f, 0.f};

  // main loop: barrier-free. B-frag address = chunk*16KB + kt*1KB + lane*16,
  // coalesced 1 KB per wave-load, L1-hit after first wave touches it.
  const char* bbase = (const char*)Wfrag + lane * 16;
  for (int ch = 0; ch < 32; ++ch) {
    float vg = v[ch * 16 + frow];
    const char* bp = bbase + (size_t)ch * 16384;

    // 2 independent accumulator chains (kt parity)
    f32x4 acc0 = {0.f, 0.f, 0.f, 0.f};
    f32x4 acc1 = {0.f, 0.f, 0.f, 0.f};
    #pragma unroll
    for (int kt = 0; kt < 16; kt += 2) {
      short8 b0 = *reinterpret_cast<const short8*>(bp + kt * 1024);
      short8 b1 = *reinterpret_cast<const short8*>(bp + (kt + 1) * 1024);
      acc0 = __builtin_amdgcn_mfma_f32_16x16x32_bf16(afrag[kt],     b0, acc0, 0, 0, 0);
      acc1 = __builtin_amdgcn_mfma_f32_16x16x32_bf16(afrag[kt + 1], b1, acc1, 0, 0, 0);
    }
    // D[m][n]: n = frow (g), m = kslot*4 + reg
    #pragma unroll
    for (int r = 0; r < 4; ++r)
      red[r] = fmaf(vg, fast_tanh(acc0[r] + acc1[r]), red[r]);
  }

  // reduce over the 16 g-lanes (frow) within each kslot group
  #pragma unroll
  for (int r = 0; r < 4; ++r) {
    #pragma unroll
    for (int d = 1; d < 16; d <<= 1)
      red[r] += __shfl_xor(red[r], d);
  }
  if (frow == 0) {
    float* sp = sLDS + wave * 16 + kslot * 4;
    sp[0] = red[0]; sp[1] = red[1]; sp[2] = red[2]; sp[3] = red[3];
  }
  __syncthreads();

  // ---- block-local softmax stats over the 128 rows ----
  if (tid < 128) {
    float s = sLDS[tid];
    float m = s;
    #pragma unroll
    for (int d = 1; d < 64; d <<= 1) m = fmaxf(m, __shfl_xor(m, d));
    if ((tid & 63) == 0) mred[tid >> 6] = m;
  }
  __syncthreads();
  const float m_loc = fmaxf(mred[0], mred[1]);
  if (tid < 128) {
    float p = __expf(sLDS[tid] - m_loc);
    pLDS[tid] = p;
    #pragma unroll
    for (int d = 1; d < 64; d <<= 1) p += __shfl_xor(p, d);
    if ((tid & 63) == 0) dred[tid >> 6] = p;
  }
  __syncthreads();

  // ---- partial numerator: thread owns h = tid; X tile is L2/L3-hot ----
  float a = 0.f;
  const float* xb = X + rowbase * H_SZ + tid;
  #pragma unroll 8
  for (int t = 0; t < 128; ++t)
    a = fmaf(pLDS[t], xb[(size_t)t * H_SZ], a);
  num[(size_t)blockIdx.x * H_SZ + tid] = a;
  if (tid == 0) {
    float2 r; r.x = m_loc; r.y = dred[0] + dred[1];
    md[blockIdx.x] = r;
  }
}

// ---- combine 32 block-partials per batch with global-max rescale ----
__global__ __launch_bounds__(512) void combine_kernel(
    const float* __restrict__ num, const float2* __restrict__ md,
    float* __restrict__ out) {
  const int b = blockIdx.x;   // 32
  const int h = threadIdx.x;  // 512
  float M = -1e30f;
  #pragma unroll
  for (int c = 0; c < 32; ++c) M = fmaxf(M, md[b * 32 + c].x);
  float den = 0.f, acc = 0.f;
  #pragma unroll 4
  for (int c = 0; c < 32; ++c) {
    float2 m2 = md[b * 32 + c];
    float w = __expf(m2.x - M);
    den += w * m2.y;
    acc = fmaf(w, num[(size_t)(b * 32 + c) * H_SZ + h], acc);
  }
  out[b * H_SZ + h] = acc / den;
}

extern "C" void kernel_launch(void* const* d_in, const int* in_sizes, int n_in,
                              void* d_out, int out_size, void* d_ws, size_t ws_size,
                              hipStream_t stream) {
  const float* X = (const float*)d_in[0];   // (32,4096,512)
  const float* W = (const float*)d_in[1];   // (512,512)
  const float* v = (const float*)d_in[2];   // (512,)
  float* out = (float*)d_out;               // (32,512) fp32
  unsigned char* ws = (unsigned char*)d_ws;

  uint4* Wfrag = (uint4*)(ws);                          // 512 KB
  float* num   = (float*)(ws + (512u << 10));           // 1024*512*4 = 2 MB
  float2* md   = (float2*)(ws + (512u << 10) + (2u << 20));  // 8 KB

  prep_w_kernel<<<128, 256, 0, stream>>>(W, Wfrag);
  score_fused_kernel<<<NROWS / 128, 512, 0, stream>>>(X, Wfrag, v, num, md);
  combine_kernel<<<B_SZ, 512, 0, stream>>>(num, md, out);
}

// Round 9
// 163.868 us; speedup vs baseline: 1.2649x; 1.2649x over previous
//
#include <hip/hip_runtime.h>
#include <hip/hip_bf16.h>

typedef __attribute__((ext_vector_type(8))) short short8;
typedef __attribute__((ext_vector_type(4))) float f32x4;

#define B_SZ 32
#define T_SZ 4096
#define H_SZ 512
#define NROWS (B_SZ * T_SZ)   // 131072

// packed fp32x2 -> bf16x2 (RNE), single v_cvt_pk_bf16_f32: a->low16, b->high16
static __device__ __forceinline__ unsigned int pack2(float a, float b) {
  unsigned int r;
  asm("v_cvt_pk_bf16_f32 %0, %1, %2" : "=v"(r) : "v"(a), "v"(b));
  return r;
}

// branch-free tanh, exact saturation at +/-inf: 1 - 2/(e^{2x}+1)
static __device__ __forceinline__ float fast_tanh(float x) {
  float e = __expf(2.0f * x);
  return 1.0f - 2.0f / (e + 1.0f);
}

// ---- W fp32 (512x512) -> bf16 in MFMA-fragment order ----
// fragment s = grow*64 + kt*4 + kslot; holds W[grow][kt*32 + kslot*8 .. +8]
// dst uint4 index = nb*1024 + kt*64 + (kslot*16 + g); a 16-g chunk = 16 KB contiguous
__global__ __launch_bounds__(256) void prep_w_kernel(
    const float* __restrict__ W, uint4* __restrict__ Wfrag) {
  int s = blockIdx.x * 256 + threadIdx.x;   // 0..32767
  int grow  = s >> 6;
  int kt    = (s >> 2) & 15;
  int kslot = s & 3;
  const float4* Wf4 = reinterpret_cast<const float4*>(W);
  float4 lo = Wf4[grow * 128 + kt * 8 + kslot * 2];
  float4 hi = Wf4[grow * 128 + kt * 8 + kslot * 2 + 1];
  uint4 u;
  u.x = pack2(lo.x, lo.y); u.y = pack2(lo.z, lo.w);
  u.z = pack2(hi.x, hi.y); u.w = pack2(hi.z, hi.w);
  int nb = grow >> 4, g = grow & 15;
  Wfrag[nb * 1024 + kt * 64 + kslot * 16 + g] = u;
}

// ---- fused: scores (MFMA) + block softmax + partial numerator ----
// 256 thr = 4 waves, wave owns 32 rows (2 rowsets) -> block M=128, grid 1024.
// A in regs full-K (128 VGPR, launch_bounds(256,2) gives the allocator room).
// B: 16-g / 16 KB chunks, TRIPLE-buffered, counted vmcnt(4) raw barriers; the
// ONLY vmem in the main loop is the stage (v comes from LDS), so the count is
// exact. Ping-pong accumulators: chunk c's MFMA burst overlaps chunk c-1's
// tanh VALU (separate pipes).
__global__ __launch_bounds__(256, 2) void score_fused_kernel(
    const float* __restrict__ X, const uint4* __restrict__ Wfrag,
    const float* __restrict__ v,
    float* __restrict__ num, float2* __restrict__ md) {
  __shared__ unsigned char WsB[3][16384];
  __shared__ float vLDS[512];
  __shared__ float sLDS[128];
  __shared__ float pLDS[128];
  __shared__ float mred[2], dred[2];

  const int tid   = threadIdx.x;
  const int lane  = tid & 63;
  const int wave  = tid >> 6;
  const int frow  = lane & 15;   // A: m row / B: g col
  const int kslot = lane >> 4;
  const size_t rowbase = (size_t)blockIdx.x * 128;

  // stage chunk c into buffer c%3: 16 KB linear, 4 KB (4 loads) per wave
  #define STAGE(c)                                                              \
    {                                                                           \
      const char* src = (const char*)Wfrag + (size_t)(c) * 16384 +              \
                        wave * 4096 + lane * 16;                                \
      unsigned char* dst = &WsB[(c) % 3][wave * 4096];                          \
      _Pragma("unroll")                                                         \
      for (int i = 0; i < 4; ++i)                                               \
        __builtin_amdgcn_global_load_lds((const unsigned int*)(src + i * 1024), \
                                         (unsigned int*)(dst + i * 1024), 16, 0, 0); \
    }

  STAGE(0);
  STAGE(1);
  // v -> LDS once (512 floats); main loop reads it via ds_read (lgkmcnt, not vmcnt)
  reinterpret_cast<float2*>(vLDS)[tid] = reinterpret_cast<const float2*>(v)[tid];

  // A fragments, 2 rowsets: X[arow][kt*32 + kslot*8 .. +8], bf16-packed (128 VGPR)
  short8 afrag0[16], afrag1[16];
  {
    const float4* xr0 = reinterpret_cast<const float4*>(X + (rowbase + wave * 32 + frow) * H_SZ);
    const float4* xr1 = reinterpret_cast<const float4*>(X + (rowbase + wave * 32 + 16 + frow) * H_SZ);
    #pragma unroll
    for (int kt = 0; kt < 16; ++kt) {
      float4 lo0 = xr0[kt * 8 + kslot * 2];
      float4 hi0 = xr0[kt * 8 + kslot * 2 + 1];
      union { uint4 u; short8 s; } c0;
      c0.u.x = pack2(lo0.x, lo0.y); c0.u.y = pack2(lo0.z, lo0.w);
      c0.u.z = pack2(hi0.x, hi0.y); c0.u.w = pack2(hi0.z, hi0.w);
      afrag0[kt] = c0.s;
      float4 lo1 = xr1[kt * 8 + kslot * 2];
      float4 hi1 = xr1[kt * 8 + kslot * 2 + 1];
      union { uint4 u; short8 s; } c1;
      c1.u.x = pack2(lo1.x, lo1.y); c1.u.y = pack2(lo1.z, lo1.w);
      c1.u.z = pack2(hi1.x, hi1.y); c1.u.w = pack2(hi1.z, hi1.w);
      afrag1[kt] = c1.s;
    }
  }
  asm volatile("s_waitcnt vmcnt(0) lgkmcnt(0)" ::: "memory");
  __builtin_amdgcn_s_barrier();
  __builtin_amdgcn_sched_barrier(0);

  float red0[4] = {0.f, 0.f, 0.f, 0.f};
  float red1[4] = {0.f, 0.f, 0.f, 0.f};

  // ping-pong state: previous chunk's accumulators + its vg
  f32x4 accP[2][2];
  float vgP = 0.f;

  for (int ch = 0; ch < 32; ++ch) {
    if (ch + 2 < 32) STAGE(ch + 2);
    float vg = vLDS[ch * 16 + frow];   // LDS read — does not touch vmcnt

    f32x4 accC[2][2];   // [rowset][kt-parity]
    #pragma unroll
    for (int a = 0; a < 2; ++a)
      #pragma unroll
      for (int p = 0; p < 2; ++p)
        accC[a][p] = (f32x4){0.f, 0.f, 0.f, 0.f};

    const unsigned char* bb = &WsB[ch % 3][lane * 16];
    #pragma unroll
    for (int kt = 0; kt < 16; ++kt) {
      short8 b = *reinterpret_cast<const short8*>(bb + kt * 1024);  // linear, conflict-free
      const int p = kt & 1;
      accC[0][p] = __builtin_amdgcn_mfma_f32_16x16x32_bf16(afrag0[kt], b, accC[0][p], 0, 0, 0);
      accC[1][p] = __builtin_amdgcn_mfma_f32_16x16x32_bf16(afrag1[kt], b, accC[1][p], 0, 0, 0);
    }

    // deferred epilogue: tanh of chunk ch-1 (independent of this chunk's
    // ds_reads/MFMAs -> VALU overlaps the MFMA pipe)
    if (ch > 0) {
      #pragma unroll
      for (int r = 0; r < 4; ++r) {
        red0[r] = fmaf(vgP, fast_tanh(accP[0][0][r] + accP[0][1][r]), red0[r]);
        red1[r] = fmaf(vgP, fast_tanh(accP[1][0][r] + accP[1][1][r]), red1[r]);
      }
    }
    #pragma unroll
    for (int a = 0; a < 2; ++a)
      #pragma unroll
      for (int p = 0; p < 2; ++p)
        accP[a][p] = accC[a][p];
    vgP = vg;

    // counted barrier: all but the newest 4 stage-loads complete -> chunk ch+1
    // resident; chunk ch+2 stays in flight. Drain only at the very end.
    if (ch < 31) {
      if (ch < 30) {
        asm volatile("s_waitcnt vmcnt(4)" ::: "memory");
      } else {
        asm volatile("s_waitcnt vmcnt(0)" ::: "memory");
      }
      __builtin_amdgcn_s_barrier();
      __builtin_amdgcn_sched_barrier(0);
    }
  }
  #undef STAGE

  // final deferred epilogue (chunk 31)
  #pragma unroll
  for (int r = 0; r < 4; ++r) {
    red0[r] = fmaf(vgP, fast_tanh(accP[0][0][r] + accP[0][1][r]), red0[r]);
    red1[r] = fmaf(vgP, fast_tanh(accP[1][0][r] + accP[1][1][r]), red1[r]);
  }

  // reduce over the 16 g-lanes (frow) within each kslot group
  #pragma unroll
  for (int r = 0; r < 4; ++r) {
    #pragma unroll
    for (int d = 1; d < 16; d <<= 1) {
      red0[r] += __shfl_xor(red0[r], d);
      red1[r] += __shfl_xor(red1[r], d);
    }
  }
  if (frow == 0) {
    float* sp = sLDS + wave * 32 + kslot * 4;
    sp[0]  = red0[0]; sp[1]  = red0[1]; sp[2]  = red0[2]; sp[3]  = red0[3];
    sp[16] = red1[0]; sp[17] = red1[1]; sp[18] = red1[2]; sp[19] = red1[3];
  }
  __syncthreads();

  // ---- block-local softmax stats over the 128 rows ----
  if (tid < 128) {
    float s = sLDS[tid];
    float m = s;
    #pragma unroll
    for (int d = 1; d < 64; d <<= 1) m = fmaxf(m, __shfl_xor(m, d));
    if ((tid & 63) == 0) mred[tid >> 6] = m;
  }
  __syncthreads();
  const float m_loc = fmaxf(mred[0], mred[1]);
  if (tid < 128) {
    float p = __expf(sLDS[tid] - m_loc);
    pLDS[tid] = p;
    #pragma unroll
    for (int d = 1; d < 64; d <<= 1) p += __shfl_xor(p, d);
    if ((tid & 63) == 0) dred[tid >> 6] = p;
  }
  __syncthreads();

  // ---- partial numerator: thread owns h = 2*tid..2*tid+1; X tile L2/L3-hot ----
  {
    float ax = 0.f, ay = 0.f;
    const float2* xb = reinterpret_cast<const float2*>(X + rowbase * H_SZ) + tid;
    #pragma unroll 8
    for (int t = 0; t < 128; ++t) {
      float p = pLDS[t];
      float2 xv = xb[(size_t)t * (H_SZ / 2)];
      ax = fmaf(p, xv.x, ax);
      ay = fmaf(p, xv.y, ay);
    }
    float2 r; r.x = ax; r.y = ay;
    reinterpret_cast<float2*>(num + (size_t)blockIdx.x * H_SZ)[tid] = r;
  }
  if (tid == 0) {
    float2 r; r.x = m_loc; r.y = dred[0] + dred[1];
    md[blockIdx.x] = r;
  }
}

// ---- combine 32 block-partials per batch with global-max rescale ----
__global__ __launch_bounds__(512) void combine_kernel(
    const float* __restrict__ num, const float2* __restrict__ md,
    float* __restrict__ out) {
  const int b = blockIdx.x;   // 32
  const int h = threadIdx.x;  // 512
  float M = -1e30f;
  #pragma unroll
  for (int c = 0; c < 32; ++c) M = fmaxf(M, md[b * 32 + c].x);
  float den = 0.f, acc = 0.f;
  #pragma unroll 4
  for (int c = 0; c < 32; ++c) {
    float2 m2 = md[b * 32 + c];
    float w = __expf(m2.x - M);
    den += w * m2.y;
    acc = fmaf(w, num[(size_t)(b * 32 + c) * H_SZ + h], acc);
  }
  out[b * H_SZ + h] = acc / den;
}

extern "C" void kernel_launch(void* const* d_in, const int* in_sizes, int n_in,
                              void* d_out, int out_size, void* d_ws, size_t ws_size,
                              hipStream_t stream) {
  const float* X = (const float*)d_in[0];   // (32,4096,512)
  const float* W = (const float*)d_in[1];   // (512,512)
  const float* v = (const float*)d_in[2];   // (512,)
  float* out = (float*)d_out;               // (32,512) fp32
  unsigned char* ws = (unsigned char*)d_ws;

  uint4* Wfrag = (uint4*)(ws);                          // 512 KB
  float* num   = (float*)(ws + (512u << 10));           // 1024*512*4 = 2 MB
  float2* md   = (float2*)(ws + (512u << 10) + (2u << 20));  // 8 KB

  prep_w_kernel<<<128, 256, 0, stream>>>(W, Wfrag);
  score_fused_kernel<<<NROWS / 128, 256, 0, stream>>>(X, Wfrag, v, num, md);
  combine_kernel<<<B_SZ, 512, 0, stream>>>(num, md, out);
}

// Round 10
// 163.626 us; speedup vs baseline: 1.2668x; 1.0015x over previous
//
#include <hip/hip_runtime.h>
#include <hip/hip_bf16.h>

typedef __attribute__((ext_vector_type(8))) short short8;
typedef __attribute__((ext_vector_type(4))) float f32x4;

#define B_SZ 32
#define T_SZ 4096
#define H_SZ 512
#define NROWS (B_SZ * T_SZ)   // 131072

// packed fp32x2 -> bf16x2 (RNE), single v_cvt_pk_bf16_f32
static __device__ __forceinline__ unsigned int pack2(float a, float b) {
  unsigned int r;
  asm("v_cvt_pk_bf16_f32 %0, %1, %2" : "=v"(r) : "v"(a), "v"(b));
  return r;
}

// branch-free tanh, exact saturation at +/-inf: 1 - 2/(e^{2x}+1)
static __device__ __forceinline__ float fast_tanh(float x) {
  float e = __expf(2.0f * x);
  return 1.0f - 2.0f / (e + 1.0f);
}

// ---- W fp32 (512x512) -> bf16 in MFMA-fragment order ----
// fragment s = grow*64 + kt*4 + kslot; holds W[grow][kt*32 + kslot*8 .. +8]
// dst uint4 index = nb*1024 + kt*64 + (kslot*16 + g); 16-g chunk = 16 KB contiguous
__global__ __launch_bounds__(256) void prep_w_kernel(
    const float* __restrict__ W, uint4* __restrict__ Wfrag) {
  int s = blockIdx.x * 256 + threadIdx.x;   // 0..32767
  int grow  = s >> 6;
  int kt    = (s >> 2) & 15;
  int kslot = s & 3;
  const float4* Wf4 = reinterpret_cast<const float4*>(W);
  float4 lo = Wf4[grow * 128 + kt * 8 + kslot * 2];
  float4 hi = Wf4[grow * 128 + kt * 8 + kslot * 2 + 1];
  uint4 u;
  u.x = pack2(lo.x, lo.y); u.y = pack2(lo.z, lo.w);
  u.z = pack2(hi.x, hi.y); u.w = pack2(hi.z, hi.w);
  int nb = grow >> 4, g = grow & 15;
  Wfrag[nb * 1024 + kt * 64 + kslot * 16 + g] = u;
}

// ---- fused: scores (MFMA, 8-phase-style fine interleave) + softmax + num ----
// 256 thr = 4 waves, wave owns 32 rows -> block M=128, grid 1024, 2 blocks/CU.
// Per 16-g chunk: 4 phases of {4 ds_read, 1 stage-issue, bar, prio, 8 MFMA,
// prio, bar}; triple-buffered B; ONE counted vmcnt(4) per chunk boundary.
__global__ __launch_bounds__(256, 2) void score_fused_kernel(
    const float* __restrict__ X, const uint4* __restrict__ Wfrag,
    const float* __restrict__ v,
    float* __restrict__ num, float2* __restrict__ md) {
  __shared__ unsigned char WsB[3][16384];
  __shared__ float vLDS[512];
  __shared__ float sLDS[128];
  __shared__ float pLDS[128];
  __shared__ float mred[2], dred[2];

  const int tid   = threadIdx.x;
  const int lane  = tid & 63;
  const int wave  = tid >> 6;
  const int frow  = lane & 15;   // A: m row / B: g col
  const int kslot = lane >> 4;
  const size_t rowbase = (size_t)blockIdx.x * 128;

  // one stage round: 4 KB of chunk c (round p), 1 KB per wave
  #define STAGE_RD(c, p)                                                        \
    {                                                                           \
      const char* src = (const char*)Wfrag + (size_t)(c) * 16384 +              \
                        (p) * 4096 + wave * 1024 + lane * 16;                   \
      unsigned char* dst = &WsB[(c) % 3][(p) * 4096 + wave * 1024];             \
      __builtin_amdgcn_global_load_lds((const unsigned int*)src,                \
                                       (unsigned int*)dst, 16, 0, 0);           \
    }

  // prologue: chunks 0 and 1 fully issued (8 rounds, latency hides under A)
  #pragma unroll
  for (int p = 0; p < 4; ++p) STAGE_RD(0, p);
  #pragma unroll
  for (int p = 0; p < 4; ++p) STAGE_RD(1, p);
  // v -> LDS (ds traffic only; keeps main-loop vmcnt FIFO = stage-only)
  reinterpret_cast<float2*>(vLDS)[tid] = reinterpret_cast<const float2*>(v)[tid];

  // A fragments, 2 rowsets: X[arow][kt*32 + kslot*8 .. +8], bf16-packed (128 VGPR)
  short8 afrag0[16], afrag1[16];
  {
    const float4* xr0 = reinterpret_cast<const float4*>(X + (rowbase + wave * 32 + frow) * H_SZ);
    const float4* xr1 = reinterpret_cast<const float4*>(X + (rowbase + wave * 32 + 16 + frow) * H_SZ);
    #pragma unroll
    for (int kt = 0; kt < 16; ++kt) {
      float4 lo0 = xr0[kt * 8 + kslot * 2];
      float4 hi0 = xr0[kt * 8 + kslot * 2 + 1];
      union { uint4 u; short8 s; } c0;
      c0.u.x = pack2(lo0.x, lo0.y); c0.u.y = pack2(lo0.z, lo0.w);
      c0.u.z = pack2(hi0.x, hi0.y); c0.u.w = pack2(hi0.z, hi0.w);
      afrag0[kt] = c0.s;
      float4 lo1 = xr1[kt * 8 + kslot * 2];
      float4 hi1 = xr1[kt * 8 + kslot * 2 + 1];
      union { uint4 u; short8 s; } c1;
      c1.u.x = pack2(lo1.x, lo1.y); c1.u.y = pack2(lo1.z, lo1.w);
      c1.u.z = pack2(hi1.x, hi1.y); c1.u.w = pack2(hi1.z, hi1.w);
      afrag1[kt] = c1.s;
    }
  }
  // chunk 0 landed (newest 4 = chunk 1 may stay in flight); vLDS visible
  asm volatile("s_waitcnt vmcnt(4) lgkmcnt(0)" ::: "memory");
  __builtin_amdgcn_s_barrier();
  __builtin_amdgcn_sched_barrier(0);

  float red0[4] = {0.f, 0.f, 0.f, 0.f};
  float red1[4] = {0.f, 0.f, 0.f, 0.f};

  for (int ch = 0; ch < 32; ++ch) {
    const int stage_c = ch + 2;
    const unsigned char* bb = &WsB[ch % 3][lane * 16];
    float vg = vLDS[ch * 16 + frow];

    f32x4 acc[2][2];   // [rowset][kt-parity]
    #pragma unroll
    for (int a = 0; a < 2; ++a)
      #pragma unroll
      for (int p = 0; p < 2; ++p)
        acc[a][p] = (f32x4){0.f, 0.f, 0.f, 0.f};

    #pragma unroll
    for (int ph = 0; ph < 4; ++ph) {
      // (a) ds-load this phase's 4 B-frags into regs
      short8 b0 = *reinterpret_cast<const short8*>(bb + (ph * 4 + 0) * 1024);
      short8 b1 = *reinterpret_cast<const short8*>(bb + (ph * 4 + 1) * 1024);
      short8 b2 = *reinterpret_cast<const short8*>(bb + (ph * 4 + 2) * 1024);
      short8 b3 = *reinterpret_cast<const short8*>(bb + (ph * 4 + 3) * 1024);
      // (b) stage one round of chunk ch+2
      if (stage_c < 32) STAGE_RD(stage_c, ph);
      __builtin_amdgcn_s_barrier();
      __builtin_amdgcn_sched_barrier(0);
      // (c) MFMA cluster (compiler inserts the lgkmcnt for b0..b3)
      __builtin_amdgcn_s_setprio(1);
      {
        const int k0 = ph * 4;
        acc[0][(k0 + 0) & 1] = __builtin_amdgcn_mfma_f32_16x16x32_bf16(afrag0[k0 + 0], b0, acc[0][(k0 + 0) & 1], 0, 0, 0);
        acc[1][(k0 + 0) & 1] = __builtin_amdgcn_mfma_f32_16x16x32_bf16(afrag1[k0 + 0], b0, acc[1][(k0 + 0) & 1], 0, 0, 0);
        acc[0][(k0 + 1) & 1] = __builtin_amdgcn_mfma_f32_16x16x32_bf16(afrag0[k0 + 1], b1, acc[0][(k0 + 1) & 1], 0, 0, 0);
        acc[1][(k0 + 1) & 1] = __builtin_amdgcn_mfma_f32_16x16x32_bf16(afrag1[k0 + 1], b1, acc[1][(k0 + 1) & 1], 0, 0, 0);
        acc[0][(k0 + 2) & 1] = __builtin_amdgcn_mfma_f32_16x16x32_bf16(afrag0[k0 + 2], b2, acc[0][(k0 + 2) & 1], 0, 0, 0);
        acc[1][(k0 + 2) & 1] = __builtin_amdgcn_mfma_f32_16x16x32_bf16(afrag1[k0 + 2], b2, acc[1][(k0 + 2) & 1], 0, 0, 0);
        acc[0][(k0 + 3) & 1] = __builtin_amdgcn_mfma_f32_16x16x32_bf16(afrag0[k0 + 3], b3, acc[0][(k0 + 3) & 1], 0, 0, 0);
        acc[1][(k0 + 3) & 1] = __builtin_amdgcn_mfma_f32_16x16x32_bf16(afrag1[k0 + 3], b3, acc[1][(k0 + 3) & 1], 0, 0, 0);
      }
      __builtin_amdgcn_s_setprio(0);
      __builtin_amdgcn_s_barrier();
      __builtin_amdgcn_sched_barrier(0);
    }

    // chunk epilogue: D[m][n] n=frow, m=kslot*4+reg
    #pragma unroll
    for (int r = 0; r < 4; ++r) {
      red0[r] = fmaf(vg, fast_tanh(acc[0][0][r] + acc[0][1][r]), red0[r]);
      red1[r] = fmaf(vg, fast_tanh(acc[1][0][r] + acc[1][1][r]), red1[r]);
    }

    // chunk boundary: counted wait — chunk ch+1 resident, ch+2 stays in flight
    if (ch < 31) {
      if (ch < 30) {
        asm volatile("s_waitcnt vmcnt(4)" ::: "memory");
      } else {
        asm volatile("s_waitcnt vmcnt(0)" ::: "memory");
      }
      __builtin_amdgcn_s_barrier();
      __builtin_amdgcn_sched_barrier(0);
    }
  }
  #undef STAGE_RD

  // reduce over the 16 g-lanes (frow) within each kslot group
  #pragma unroll
  for (int r = 0; r < 4; ++r) {
    #pragma unroll
    for (int d = 1; d < 16; d <<= 1) {
      red0[r] += __shfl_xor(red0[r], d);
      red1[r] += __shfl_xor(red1[r], d);
    }
  }
  if (frow == 0) {
    float* sp = sLDS + wave * 32 + kslot * 4;
    sp[0]  = red0[0]; sp[1]  = red0[1]; sp[2]  = red0[2]; sp[3]  = red0[3];
    sp[16] = red1[0]; sp[17] = red1[1]; sp[18] = red1[2]; sp[19] = red1[3];
  }
  __syncthreads();

  // ---- block-local softmax stats over the 128 rows ----
  if (tid < 128) {
    float s = sLDS[tid];
    float m = s;
    #pragma unroll
    for (int d = 1; d < 64; d <<= 1) m = fmaxf(m, __shfl_xor(m, d));
    if ((tid & 63) == 0) mred[tid >> 6] = m;
  }
  __syncthreads();
  const float m_loc = fmaxf(mred[0], mred[1]);
  if (tid < 128) {
    float p = __expf(sLDS[tid] - m_loc);
    pLDS[tid] = p;
    #pragma unroll
    for (int d = 1; d < 64; d <<= 1) p += __shfl_xor(p, d);
    if ((tid & 63) == 0) dred[tid >> 6] = p;
  }
  __syncthreads();

  // ---- partial numerator: thread owns h = 2*tid..2*tid+1; X tile L2/L3-hot ----
  {
    float ax = 0.f, ay = 0.f;
    const float2* xb = reinterpret_cast<const float2*>(X + rowbase * H_SZ) + tid;
    #pragma unroll 8
    for (int t = 0; t < 128; ++t) {
      float p = pLDS[t];
      float2 xv = xb[(size_t)t * (H_SZ / 2)];
      ax = fmaf(p, xv.x, ax);
      ay = fmaf(p, xv.y, ay);
    }
    float2 r; r.x = ax; r.y = ay;
    reinterpret_cast<float2*>(num + (size_t)blockIdx.x * H_SZ)[tid] = r;
  }
  if (tid == 0) {
    float2 r; r.x = m_loc; r.y = dred[0] + dred[1];
    md[blockIdx.x] = r;
  }
}

// ---- combine 32 block-partials per batch with global-max rescale ----
__global__ __launch_bounds__(512) void combine_kernel(
    const float* __restrict__ num, const float2* __restrict__ md,
    float* __restrict__ out) {
  const int b = blockIdx.x;   // 32
  const int h = threadIdx.x;  // 512
  float M = -1e30f;
  #pragma unroll
  for (int c = 0; c < 32; ++c) M = fmaxf(M, md[b * 32 + c].x);
  float den = 0.f, acc = 0.f;
  #pragma unroll 4
  for (int c = 0; c < 32; ++c) {
    float2 m2 = md[b * 32 + c];
    float w = __expf(m2.x - M);
    den += w * m2.y;
    acc = fmaf(w, num[(size_t)(b * 32 + c) * H_SZ + h], acc);
  }
  out[b * H_SZ + h] = acc / den;
}

extern "C" void kernel_launch(void* const* d_in, const int* in_sizes, int n_in,
                              void* d_out, int out_size, void* d_ws, size_t ws_size,
                              hipStream_t stream) {
  const float* X = (const float*)d_in[0];   // (32,4096,512)
  const float* W = (const float*)d_in[1];   // (512,512)
  const float* v = (const float*)d_in[2];   // (512,)
  float* out = (float*)d_out;               // (32,512) fp32
  unsigned char* ws = (unsigned char*)d_ws;

  uint4* Wfrag = (uint4*)(ws);                          // 512 KB
  float* num   = (float*)(ws + (512u << 10));           // 2 MB
  float2* md   = (float2*)(ws + (512u << 10) + (2u << 20));  // 8 KB

  prep_w_kernel<<<128, 256, 0, stream>>>(W, Wfrag);
  score_fused_kernel<<<NROWS / 128, 256, 0, stream>>>(X, Wfrag, v, num, md);
  combine_kernel<<<B_SZ, 512, 0, stream>>>(num, md, out);
}

// Round 11
// 155.137 us; speedup vs baseline: 1.3361x; 1.0547x over previous
//
#include <hip/hip_runtime.h>
#include <hip/hip_bf16.h>

typedef __attribute__((ext_vector_type(8))) short short8;
typedef __attribute__((ext_vector_type(4))) float f32x4;

#define B_SZ 32
#define T_SZ 4096
#define H_SZ 512
#define NROWS (B_SZ * T_SZ)   // 131072
#define RB 64                 // rows per block

// packed fp32x2 -> bf16x2 (RNE)
static __device__ __forceinline__ unsigned int pack2(float a, float b) {
  unsigned int r;
  asm("v_cvt_pk_bf16_f32 %0, %1, %2" : "=v"(r) : "v"(a), "v"(b));
  return r;
}
// branch-free tanh, exact saturation: 1 - 2/(e^{2x}+1)
static __device__ __forceinline__ float fast_tanh(float x) {
  float e = __expf(2.0f * x);
  return 1.0f - 2.0f / (e + 1.0f);
}

// ---- W fp32 (512x512) -> bf16 fragments, K-CHUNK-MAJOR layout ----
// s = kc*2048 + gf*64 + kslot*16 + frow  (uint4 index)
// holds W[g = gf*16+frow][kc*32 + kslot*8 .. +8] as 8 bf16.
// One K-chunk (all 512 g, 32 k) = 2048 uint4 = 32 KB contiguous.
__global__ __launch_bounds__(256) void prep_w_kernel(
    const float* __restrict__ W, uint4* __restrict__ Wfrag) {
  int s = blockIdx.x * 256 + threadIdx.x;   // 0..32767
  int frow  = s & 15;
  int kslot = (s >> 4) & 3;
  int gf    = (s >> 6) & 31;
  int kc    = s >> 11;
  int g  = gf * 16 + frow;
  int k0 = kc * 32 + kslot * 8;
  const float4* Wf4 = reinterpret_cast<const float4*>(W);
  float4 lo = Wf4[g * 128 + (k0 >> 2)];
  float4 hi = Wf4[g * 128 + (k0 >> 2) + 1];
  uint4 u;
  u.x = pack2(lo.x, lo.y); u.y = pack2(lo.z, lo.w);
  u.z = pack2(hi.x, hi.y); u.w = pack2(hi.z, hi.w);
  Wfrag[s] = u;
}

// ---- fused K-streaming kernel ----
// 512 thr = 8 waves. Wave (rg = wave>>2, gg = wave&3): rows rg*32..+32,
// g-slice gg*128..+128. acc = energy[2 rowsets][8 gfrags] f32x4 = 64 VGPR,
// g-resident across the K loop. Per K-chunk (32 k): A-tile 64x32 fp32 ->
// bf16 LDS (4 KB, reg-staged, shared by the 4 g-waves), B-tile 32 KB via
// linear global_load_lds. Double-buffered, issue-early/write-late.
__global__ __launch_bounds__(512, 4) void score_fused_kernel(
    const float* __restrict__ X, const uint4* __restrict__ Wfrag,
    const float* __restrict__ v,
    float* __restrict__ num, float2* __restrict__ md) {
  __shared__ unsigned char WsA[2][4096];    // [rs(4)][lane(64)][16B]
  __shared__ unsigned char WsB[2][32768];   // [gf(32)][lane(64)][16B]
  __shared__ float sp[4][RB];
  __shared__ float pLDS[RB];

  const int tid   = threadIdx.x;
  const int lane  = tid & 63;
  const int wave  = tid >> 6;
  const int frow  = lane & 15;
  const int kslot = lane >> 4;
  const int rg    = wave >> 2;   // row-group 0..1
  const int gg    = wave & 3;    // g-group 0..3
  const size_t rowbase = (size_t)blockIdx.x * RB;

  // A staging geometry: thread t handles row=t>>3, k-quarter qq=t&7
  const int arow = tid >> 3;
  const int aqq  = tid & 7;
  const float4* Af4 = reinterpret_cast<const float4*>(X) + (rowbase + arow) * 128 + aqq;
  const int awoff = (arow >> 4) * 1024 + (((aqq >> 1) * 16 + (arow & 15)) << 4) + ((aqq & 1) << 3);

  // B staging: 4 x 16B global_load_lds per thread per chunk (linear)
  #define STAGE_B(kc, buf)                                                      \
    {                                                                           \
      const char* src = (const char*)Wfrag + (size_t)(kc) * 32768 + tid * 16;   \
      unsigned char* dst = &WsB[buf][tid * 16];                                 \
      _Pragma("unroll")                                                         \
      for (int i = 0; i < 4; ++i)                                               \
        __builtin_amdgcn_global_load_lds((const unsigned int*)(src + i * 8192), \
                                         (unsigned int*)(dst + i * 8192), 16, 0, 0); \
    }
  #define WRITE_A(reg, buf)                                                     \
    {                                                                           \
      uint2 w2; w2.x = pack2((reg).x, (reg).y); w2.y = pack2((reg).z, (reg).w); \
      *reinterpret_cast<uint2*>(&WsA[buf][awoff]) = w2;                         \
    }

  // v-slice into regs: vv[j] = v[(gg*8+j)*16 + frow]
  float vv[8];
  #pragma unroll
  for (int j = 0; j < 8; ++j) vv[j] = v[(gg * 8 + j) * 16 + frow];

  // prologue: chunk 0
  float4 a0 = Af4[0];
  STAGE_B(0, 0);
  asm volatile("s_waitcnt vmcnt(0)" ::: "memory");
  WRITE_A(a0, 0);
  __syncthreads();

  f32x4 accA[8], accB[8];   // [gfrag] for rowset 0 / 1
  #pragma unroll
  for (int j = 0; j < 8; ++j) {
    accA[j] = (f32x4){0.f, 0.f, 0.f, 0.f};
    accB[j] = (f32x4){0.f, 0.f, 0.f, 0.f};
  }

  int cur = 0;
  for (int kc = 0; kc < 16; ++kc) {
    float4 a1;
    if (kc < 15) {              // issue-early: next A (1 float4) + next B (4 glds)
      a1 = Af4[(kc + 1) * 8];
      STAGE_B(kc + 1, cur ^ 1);
    }
    // compute chunk kc
    const unsigned char* pa = &WsA[cur][(rg * 2) * 1024 + lane * 16];
    short8 af0 = *reinterpret_cast<const short8*>(pa);
    short8 af1 = *reinterpret_cast<const short8*>(pa + 1024);
    const unsigned char* pb = &WsB[cur][(gg * 8) * 1024 + lane * 16];
    #pragma unroll
    for (int j = 0; j < 8; ++j) {
      short8 bf = *reinterpret_cast<const short8*>(pb + j * 1024);
      accA[j] = __builtin_amdgcn_mfma_f32_16x16x32_bf16(af0, bf, accA[j], 0, 0, 0);
      accB[j] = __builtin_amdgcn_mfma_f32_16x16x32_bf16(af1, bf, accB[j], 0, 0, 0);
    }
    if (kc < 15) {              // write-late: A lands after compute covered latency
      asm volatile("s_waitcnt vmcnt(0)" ::: "memory");
      WRITE_A(a1, cur ^ 1);
    }
    __syncthreads();
    cur ^= 1;
  }
  #undef STAGE_B
  #undef WRITE_A

  // epilogue: scores. lane holds D[m][n]: row = rs*16 + kslot*4 + r, g-col = frow.
  #pragma unroll
  for (int rs = 0; rs < 2; ++rs) {
    #pragma unroll
    for (int r = 0; r < 4; ++r) {
      float s = 0.f;
      #pragma unroll
      for (int j = 0; j < 8; ++j) {
        float e = (rs == 0) ? accA[j][r] : accB[j][r];
        s = fmaf(vv[j], fast_tanh(e), s);
      }
      #pragma unroll
      for (int d = 1; d < 16; d <<= 1) s += __shfl_xor(s, d);
      if (frow == 0) sp[gg][rg * 32 + rs * 16 + kslot * 4 + r] = s;
    }
  }
  __syncthreads();

  // block-local softmax over RB=64 rows (single wave)
  if (tid < 64) {
    float s = sp[0][tid] + sp[1][tid] + sp[2][tid] + sp[3][tid];
    float m = s;
    #pragma unroll
    for (int d = 1; d < 64; d <<= 1) m = fmaxf(m, __shfl_xor(m, d));
    float p = __expf(s - m);
    pLDS[tid] = p;
    float den = p;
    #pragma unroll
    for (int d = 1; d < 64; d <<= 1) den += __shfl_xor(den, d);
    if (tid == 0) {
      float2 r2; r2.x = m; r2.y = den;
      md[blockIdx.x] = r2;
    }
  }
  __syncthreads();

  // partial numerator: thread owns h = tid; X tile L2/L3-hot
  {
    float a = 0.f;
    const float* xb = X + rowbase * H_SZ + tid;
    #pragma unroll 8
    for (int t = 0; t < RB; ++t)
      a = fmaf(pLDS[t], xb[(size_t)t * H_SZ], a);
    num[(size_t)blockIdx.x * H_SZ + tid] = a;
  }
}

// ---- combine 64 block-partials per batch with global-max rescale ----
__global__ __launch_bounds__(512) void combine_kernel(
    const float* __restrict__ num, const float2* __restrict__ md,
    float* __restrict__ out) {
  const int b = blockIdx.x;   // 32
  const int h = threadIdx.x;  // 512
  float M = -1e30f;
  #pragma unroll 8
  for (int c = 0; c < 64; ++c) M = fmaxf(M, md[b * 64 + c].x);
  float den = 0.f, acc = 0.f;
  #pragma unroll 4
  for (int c = 0; c < 64; ++c) {
    float2 m2 = md[b * 64 + c];
    float w = __expf(m2.x - M);
    den += w * m2.y;
    acc = fmaf(w, num[(size_t)(b * 64 + c) * H_SZ + h], acc);
  }
  out[b * H_SZ + h] = acc / den;
}

extern "C" void kernel_launch(void* const* d_in, const int* in_sizes, int n_in,
                              void* d_out, int out_size, void* d_ws, size_t ws_size,
                              hipStream_t stream) {
  const float* X = (const float*)d_in[0];   // (32,4096,512)
  const float* W = (const float*)d_in[1];   // (512,512)
  const float* v = (const float*)d_in[2];   // (512,)
  float* out = (float*)d_out;               // (32,512) fp32
  unsigned char* ws = (unsigned char*)d_ws;

  uint4* Wfrag = (uint4*)(ws);                               // 512 KB
  float* num   = (float*)(ws + (512u << 10));                // 2048*512*4 = 4 MB
  float2* md   = (float2*)(ws + (512u << 10) + (4u << 20));  // 16 KB

  prep_w_kernel<<<128, 256, 0, stream>>>(W, Wfrag);
  score_fused_kernel<<<NROWS / RB, 512, 0, stream>>>(X, Wfrag, v, num, md);
  combine_kernel<<<B_SZ, 512, 0, stream>>>(num, md, out);
}